// Round 2
// baseline (11441.826 us; speedup 1.0000x reference)
//
#include <hip/hip_runtime.h>

// Problem constants
#define Bn 4
#define Ln 256
#define Dn 256
#define Wn 8
#define BLD (Bn*Ln*Dn)   // 262144
#define BDD (Bn*Dn*Dn)   // 262144

// -------------------------------------------------------------------------
// kphi (elementwise poly) + gamma (GEMV + sigmoid)
// -------------------------------------------------------------------------
__global__ __launch_bounds__(256) void kphi_gamma_kernel(
    const float* __restrict__ k_al, const float* __restrict__ x,
    const float* __restrict__ poly, const float* __restrict__ gW,
    const float* __restrict__ gb, float* __restrict__ kphi,
    float* __restrict__ gamma)
{
    int wg = blockIdx.x, tid = threadIdx.x;
    int wave = tid >> 6, lane = tid & 63;
    int n = wg * 4 + wave;                 // token index 0..1023
    float gacc = 0.f;
#pragma unroll
    for (int c = 0; c < 4; ++c) {
        int e = lane + 64 * c;
        float kv = k_al[n * Dn + e];
        kphi[n * Dn + e] = poly[e] * kv + poly[Dn + e] * kv * kv;
        gacc += x[n * Dn + e] * gW[e];
    }
#pragma unroll
    for (int off = 32; off; off >>= 1) gacc += __shfl_xor(gacc, off);
    if (lane == 0) gamma[n] = 1.f / (1.f + expf(-(gacc + gb[0])));
}

// -------------------------------------------------------------------------
// tiled GEMM  out[n,m] = act( sum_e In[n,e]*Wm[m,e] + bias[m] )
// ACT: 0 none, 1 sigmoid, 2 sigmoid*0.1
// -------------------------------------------------------------------------
template <int ACT>
__global__ __launch_bounds__(256) void gemm_act_kernel(
    const float* __restrict__ In, const float* __restrict__ Wm,
    const float* __restrict__ bias, float* __restrict__ Out)
{
    __shared__ float ldsX[32 * 64];
    __shared__ float ldsW[64 * 65];
    int n0 = blockIdx.x * 32;
    int m0 = blockIdx.y * 64;
    int tid = threadIdx.x;
    float acc[8] = {0, 0, 0, 0, 0, 0, 0, 0};
    for (int j0 = 0; j0 < 256; j0 += 64) {
#pragma unroll
        for (int q = 0; q < 2; ++q) {
            int fi = tid + 256 * q; int row = fi >> 4; int c4 = (fi & 15) << 2;
            *(float4*)&ldsX[row * 64 + c4] =
                *(const float4*)&In[(n0 + row) * 256 + j0 + c4];
        }
#pragma unroll
        for (int q = 0; q < 4; ++q) {
            int fi = tid + 256 * q; int row = fi >> 4; int c4 = (fi & 15) << 2;
            float4 vv = *(const float4*)&Wm[(m0 + row) * 256 + j0 + c4];
            ldsW[(c4 + 0) * 65 + row] = vv.x;
            ldsW[(c4 + 1) * 65 + row] = vv.y;
            ldsW[(c4 + 2) * 65 + row] = vv.z;
            ldsW[(c4 + 3) * 65 + row] = vv.w;
        }
        __syncthreads();
        int m = tid & 63, ng = tid >> 6;
        for (int j = 0; j < 64; ++j) {
            float wv = ldsW[j * 65 + m];
#pragma unroll
            for (int r = 0; r < 8; ++r) acc[r] += ldsX[(ng * 8 + r) * 64 + j] * wv;
        }
        __syncthreads();
    }
    int m = tid & 63, ng = tid >> 6;
    float bv = bias[m0 + m];
#pragma unroll
    for (int r = 0; r < 8; ++r) {
        float vv = acc[r] + bv;
        if (ACT == 1) vv = 1.f / (1.f + expf(-vv));
        if (ACT == 2) vv = 0.1f / (1.f + expf(-vv));
        Out[(n0 + ng * 8 + r) * 256 + m0 + m] = vv;
    }
}

// -------------------------------------------------------------------------
// prologue: init working M,S (in d_out), zero ys and per-step norm slots
// -------------------------------------------------------------------------
__global__ __launch_bounds__(256) void prologue_kernel(
    const float* __restrict__ Mprev, const float* __restrict__ Sprev,
    float* __restrict__ M, float* __restrict__ S,
    float* __restrict__ ys, float* __restrict__ normbuf)
{
    int gidx = blockIdx.x * 256 + threadIdx.x;
    ((float4*)M)[gidx] = ((const float4*)Mprev)[gidx];
    ((float4*)S)[gidx] = ((const float4*)Sprev)[gidx];
    float4 z = {0.f, 0.f, 0.f, 0.f};
    ((float4*)ys)[gidx] = z;
    if (gidx < Ln * Bn) normbuf[gidx] = 0.f;
}

// -------------------------------------------------------------------------
// per-step kernel A: err (window dots vs M) + S update + ||S||^2 atomic
// grid: 256 blocks = 4 b x 64 (8x8) 32x32 tiles of S
// -------------------------------------------------------------------------
__global__ __launch_bounds__(256) void supd_kernel(
    const float* __restrict__ kphi, const float* __restrict__ vv,
    const float* __restrict__ gamma, const float* __restrict__ theta,
    const float* __restrict__ M, float* __restrict__ S,
    float* __restrict__ normbuf, int t)
{
    __shared__ float ldsMT[64 * 33];   // [j within chunk][dd] transposed
    __shared__ float ldsK[8 * 64];     // [w][j within chunk]
    __shared__ float ldsE[8 * 32];     // scaled err
    __shared__ float ldsKe[8 * 32];    // kphi at e-block
    int b = blockIdx.x >> 6, id = blockIdx.x & 63;
    int d0 = (id >> 3) * 32, e0 = (id & 7) * 32;
    int tid = threadIdx.x;
    int w = tid >> 5, dd = tid & 31;
    int tok = t - 7 + w;
    float acc = 0.f;
    const float* Mb = M + (b * Dn + d0) * Dn;

    for (int j0 = 0; j0 < Dn; j0 += 64) {
#pragma unroll
        for (int q = 0; q < 2; ++q) {
            int fi = tid + 256 * q; int row = fi >> 4; int c4 = (fi & 15) << 2;
            float4 mv = *(const float4*)&Mb[row * Dn + j0 + c4];
            ldsMT[(c4 + 0) * 33 + row] = mv.x;
            ldsMT[(c4 + 1) * 33 + row] = mv.y;
            ldsMT[(c4 + 2) * 33 + row] = mv.z;
            ldsMT[(c4 + 3) * 33 + row] = mv.w;
        }
        if (tid < 128) {
            int ww = tid >> 4, c4 = (tid & 15) << 2;
            int tk = t - 7 + ww;
            float4 kv = {0.f, 0.f, 0.f, 0.f};
            if (tk >= 0) kv = *(const float4*)&kphi[(b * Ln + tk) * Dn + j0 + c4];
            *(float4*)&ldsK[ww * 64 + c4] = kv;
        }
        __syncthreads();
        for (int j = 0; j < 64; ++j)
            acc += ldsK[w * 64 + j] * ldsMT[j * 33 + dd];
        __syncthreads();
    }

    const int cwin = (t + 1 < Wn) ? (t + 1) : Wn;
    float gsc = 0.f, ev = 0.f, ke = 0.f;
    if (tok >= 0) {
        ev = acc - vv[(b * Ln + tok) * Dn + d0 + dd];
        gsc = gamma[b * Ln + tok] / (float)cwin;
        ke = kphi[(b * Ln + tok) * Dn + e0 + dd];
    }
    ldsE[w * 32 + dd] = ev * gsc;
    ldsKe[w * 32 + dd] = ke;
    __syncthreads();

    int ee = tid & 31, g2 = tid >> 5;
    float sumsq = 0.f;
#pragma unroll
    for (int r = 0; r < 4; ++r) {
        int d2 = g2 + 8 * r;
        float a2 = 0.f;
#pragma unroll
        for (int w2 = 0; w2 < Wn; ++w2)
            a2 += ldsE[w2 * 32 + d2] * ldsKe[w2 * 32 + ee];
        int d = d0 + d2, e = e0 + ee;
        float th = theta[(b * Ln + t) * Dn + d];
        float* sp = &S[(b * Dn + d) * Dn + e];
        float sn = th * (*sp) + a2;
        *sp = sn;
        sumsq += sn * sn;
    }
#pragma unroll
    for (int off = 32; off; off >>= 1) sumsq += __shfl_xor(sumsq, off);
    if ((tid & 63) == 0) atomicAdd(&normbuf[t * Bn + b], sumsq);
}

// -------------------------------------------------------------------------
// per-step kernel B: T = S S^T   (32x32 tiles, float4 LDS, stride 68)
// -------------------------------------------------------------------------
__global__ __launch_bounds__(256) void tmm_kernel(
    const float* __restrict__ S, float* __restrict__ T)
{
    __shared__ float Ai[32 * 68];
    __shared__ float Ak[32 * 68];
    int b = blockIdx.x >> 6, id = blockIdx.x & 63;
    int i0 = (id >> 3) * 32, k0 = (id & 7) * 32;
    int tid = threadIdx.x;
    int g = tid >> 5, kk = tid & 31;
    float acc[4] = {0, 0, 0, 0};
    const float* Sb = S + b * Dn * Dn;
    for (int j0 = 0; j0 < Dn; j0 += 64) {
#pragma unroll
        for (int q = 0; q < 2; ++q) {
            int fi = tid + 256 * q; int row = fi >> 4; int c4 = (fi & 15) << 2;
            *(float4*)&Ai[row * 68 + c4] = *(const float4*)&Sb[(i0 + row) * Dn + j0 + c4];
            *(float4*)&Ak[row * 68 + c4] = *(const float4*)&Sb[(k0 + row) * Dn + j0 + c4];
        }
        __syncthreads();
#pragma unroll 4
        for (int jq = 0; jq < 16; ++jq) {
            float4 bv = *(float4*)&Ak[kk * 68 + 4 * jq];
#pragma unroll
            for (int r = 0; r < 4; ++r) {
                float4 av = *(float4*)&Ai[(g + 8 * r) * 68 + 4 * jq];
                acc[r] += av.x * bv.x + av.y * bv.y + av.z * bv.z + av.w * bv.w;
            }
        }
        __syncthreads();
    }
#pragma unroll
    for (int r = 0; r < 4; ++r)
        T[(b * Dn + i0 + g + 8 * r) * Dn + k0 + kk] = acc[r];
}

// -------------------------------------------------------------------------
// per-step kernel C: TS = T*S ; NS = 1.5 S/n - 0.5 TS/n^3 ; M = a M - e NS ;
//                    y = M kphi_t (atomic row-partials)
// -------------------------------------------------------------------------
__global__ __launch_bounds__(256) void mupd_kernel(
    const float* __restrict__ kphi, const float* __restrict__ alpha,
    const float* __restrict__ eta, const float* __restrict__ T,
    const float* __restrict__ normbuf, const float* __restrict__ S,
    float* __restrict__ M, float* __restrict__ ys, int t)
{
    __shared__ float Ti[32 * 68];
    __shared__ float SlT[32 * 68];     // [ll][k within chunk] transposed
    int b = blockIdx.x >> 6, id = blockIdx.x & 63;
    int i0 = (id >> 3) * 32, l0 = (id & 7) * 32;
    int tid = threadIdx.x;
    int g = tid >> 5, ll = tid & 31;
    float acc[4] = {0, 0, 0, 0};
    const float* Tb = T + b * Dn * Dn;
    const float* Sb = S + b * Dn * Dn;
    for (int j0 = 0; j0 < Dn; j0 += 64) {
#pragma unroll
        for (int q = 0; q < 2; ++q) {
            int fi = tid + 256 * q;
            int row = fi >> 4; int c4 = (fi & 15) << 2;
            *(float4*)&Ti[row * 68 + c4] = *(const float4*)&Tb[(i0 + row) * Dn + j0 + c4];
            int row2 = fi >> 3; int c42 = (fi & 7) << 2;
            float4 sv = *(const float4*)&Sb[(j0 + row2) * Dn + l0 + c42];
            SlT[(c42 + 0) * 68 + row2] = sv.x;
            SlT[(c42 + 1) * 68 + row2] = sv.y;
            SlT[(c42 + 2) * 68 + row2] = sv.z;
            SlT[(c42 + 3) * 68 + row2] = sv.w;
        }
        __syncthreads();
#pragma unroll 4
        for (int jq = 0; jq < 16; ++jq) {
            float4 bv = *(float4*)&SlT[ll * 68 + 4 * jq];
#pragma unroll
            for (int r = 0; r < 4; ++r) {
                float4 av = *(float4*)&Ti[(g + 8 * r) * 68 + 4 * jq];
                acc[r] += av.x * bv.x + av.y * bv.y + av.z * bv.z + av.w * bv.w;
            }
        }
        __syncthreads();
    }
    float sq = normbuf[t * Bn + b];
    float nrm = sqrtf(sq) + 1e-7f;
    float inv_n = 1.f / nrm;
    float w1 = 1.5f * inv_n;
    float w3 = 0.5f * inv_n * inv_n * inv_n;
    int l = l0 + ll;
    float kv = kphi[(b * Ln + t) * Dn + l];
#pragma unroll
    for (int r = 0; r < 4; ++r) {
        int i = i0 + g + 8 * r;
        float s_il = Sb[i * Dn + l];
        float ns = w1 * s_il - w3 * acc[r];
        float a = alpha[(b * Ln + t) * Dn + i];
        float e = eta[(b * Ln + t) * Dn + i];
        float* mp = &M[(b * Dn + i) * Dn + l];
        float mn = a * (*mp) - e * ns;
        *mp = mn;
        float py = mn * kv;
#pragma unroll
        for (int off = 16; off; off >>= 1) py += __shfl_xor(py, off);
        if (ll == 0) atomicAdd(&ys[(b * Ln + t) * Dn + i], py);
    }
}

// -------------------------------------------------------------------------
extern "C" void kernel_launch(void* const* d_in, const int* in_sizes, int n_in,
                              void* d_out, int out_size, void* d_ws, size_t ws_size,
                              hipStream_t stream)
{
    const float* x       = (const float*)d_in[0];
    const float* k_al    = (const float*)d_in[1];
    const float* v       = (const float*)d_in[2];
    const float* M_prev  = (const float*)d_in[3];
    const float* S_prev  = (const float*)d_in[4];
    const float* poly    = (const float*)d_in[5];
    const float* alpha_W = (const float*)d_in[6];
    const float* alpha_b = (const float*)d_in[7];
    const float* eta_W   = (const float*)d_in[8];
    const float* eta_b   = (const float*)d_in[9];
    const float* theta_W = (const float*)d_in[10];
    const float* theta_b = (const float*)d_in[11];
    const float* gamma_W = (const float*)d_in[12];
    const float* gamma_b = (const float*)d_in[13];
    const float* out_W   = (const float*)d_in[14];
    const float* out_b   = (const float*)d_in[15];

    float* ws = (float*)d_ws;
    float* kphi    = ws;                 // 262144
    float* alphaB  = kphi   + BLD;       // 262144
    float* etaB    = alphaB + BLD;       // 262144
    float* thetaB  = etaB   + BLD;       // 262144
    float* gammaB  = thetaB + BLD;       // 1024
    float* Tws     = gammaB + Bn * Ln;   // 262144
    float* ysws    = Tws    + BDD;       // 262144
    float* normbuf = ysws   + BLD;       // 1024 (one slot per step x batch)

    float* out_y = (float*)d_out;        // [B,L,D]
    float* Mout  = out_y + BLD;          // [B,D,D] working M, final in-place
    float* Sout  = Mout + BDD;           // [B,D,D] working S, final in-place

    // precompute
    hipLaunchKernelGGL(kphi_gamma_kernel, dim3(256), dim3(256), 0, stream,
                       k_al, x, poly, gamma_W, gamma_b, kphi, gammaB);
    hipLaunchKernelGGL((gemm_act_kernel<1>), dim3(32, 4), dim3(256), 0, stream,
                       x, alpha_W, alpha_b, alphaB);
    hipLaunchKernelGGL((gemm_act_kernel<2>), dim3(32, 4), dim3(256), 0, stream,
                       x, eta_W, eta_b, etaB);
    hipLaunchKernelGGL((gemm_act_kernel<1>), dim3(32, 4), dim3(256), 0, stream,
                       x, theta_W, theta_b, thetaB);
    hipLaunchKernelGGL(prologue_kernel, dim3(256), dim3(256), 0, stream,
                       M_prev, S_prev, Mout, Sout, ysws, normbuf);

    // sequential scan: kernel boundaries provide grid-wide ordering
    for (int t = 0; t < Ln; ++t) {
        hipLaunchKernelGGL(supd_kernel, dim3(256), dim3(256), 0, stream,
                           kphi, v, gammaB, thetaB, Mout, Sout, normbuf, t);
        hipLaunchKernelGGL(tmm_kernel, dim3(256), dim3(256), 0, stream,
                           Sout, Tws);
        hipLaunchKernelGGL(mupd_kernel, dim3(256), dim3(256), 0, stream,
                           kphi, alphaB, etaB, Tws, normbuf, Sout, Mout, ysws, t);
    }

    // out projection
    hipLaunchKernelGGL((gemm_act_kernel<0>), dim3(32, 4), dim3(256), 0, stream,
                       ysws, out_W, out_b, out_y);
}